// Round 13
// baseline (5707.293 us; speedup 1.0000x reference)
//
#include <hip/hip_runtime.h>
#include <math.h>

// Sinkhorn EMD loss, B=32, N=1024, 3-D points, EPS=0.02, 50 iters.
// R7 = R6 (persistent cooperative kernel, per-batch spin barriers) + a
// validated fallback to the R5 multi-launch path if the cooperative launch
// is rejected (co-residency validation). Math bit-identical to R5.

#define BATCH 32
#define NPT 1024
#define EPS 0.02f
#define ITERS 50
#define RPW 8                            // rows per wave
#define ROWS_PER_WG 32                   // 4 waves * RPW
#define WG_PER_BATCH (NPT / ROWS_PER_WG) // 32
#define NWG (BATCH * WG_PER_BATCH)       // 1024
#define BAR_STRIDE 16                    // uints per batch barrier (64 B line)

static __device__ __forceinline__ float wave_max(float v) {
    #pragma unroll
    for (int off = 32; off > 0; off >>= 1)
        v = fmaxf(v, __shfl_xor(v, off, 64));
    return v;
}
static __device__ __forceinline__ float wave_sum(float v) {
    #pragma unroll
    for (int off = 32; off > 0; off >>= 1)
        v += __shfl_xor(v, off, 64);
    return v;
}

// ======================= persistent cooperative path =======================
__global__ __launch_bounds__(256, 4) void sinkhorn_fused(
    const float* __restrict__ tmpl,   // [B][N][3]
    const float* __restrict__ src,    // [B][N][3]
    float* f, float* g,               // [B][N] each (ws)
    unsigned* bar,                    // [BATCH][BAR_STRIDE] (ws, zeroed)
    float* acc, unsigned* done,       // ws, zeroed
    float* out)
{
    constexpr float LOG2E = 1.4426950408889634f;
    constexpr float LN2   = 0.6931471805599453f;
    constexpr float K2    = LOG2E / EPS;
    constexpr float LOGMARG = -6.93147180559945309f; // ln(1/1024)

    __shared__ float4 tp[NPT];   // template pts, .w = pot*K2 - S when staged
    __shared__ float4 sp[NPT];   // source pts
    __shared__ float  wred[4];

    const int tid  = threadIdx.x;
    const int wave = tid >> 6;
    const int lane = tid & 63;
    // XCD-swizzle (perf-only): co-locate a batch's 32 WGs on one XCD.
    const int xcd  = blockIdx.x & 7;
    const int slot = blockIdx.x >> 3;          // 0..127
    const int b    = xcd * 4 + (slot & 3);     // 0..31, bijective
    const int wgb  = slot >> 2;                // 0..31

    const float* tP = tmpl + (size_t)b * NPT * 3;
    const float* sP = src  + (size_t)b * NPT * 3;
    float* fb = f + b * NPT;
    float* gb = g + b * NPT;
    unsigned* cnt = bar + b * BAR_STRIDE;

    // Stage both point clouds ONCE.
    #pragma unroll
    for (int r = 0; r < 4; ++r) {
        int j = tid + 256 * r;
        tp[j] = make_float4(tP[3*j], tP[3*j+1], tP[3*j+2], 0.f);
        sp[j] = make_float4(sP[3*j], sP[3*j+1], sP[3*j+2], 0.f);
    }
    __syncthreads();

    const int i0 = wgb * ROWS_PER_WG + wave * RPW;

    // ---- per-batch barrier: monotonic counter, release/acquire fences ----
    auto barrier = [&](int phase) {
        __syncthreads();                       // all WG stores issued
        if (tid == 0) {
            __threadfence();                   // release (agent scope)
            atomicAdd(cnt, 1u);
            const unsigned target = (unsigned)phase * WG_PER_BATCH;
            while (__hip_atomic_load(cnt, __ATOMIC_ACQUIRE,
                                     __HIP_MEMORY_SCOPE_AGENT) < target)
                __builtin_amdgcn_s_sleep(4);
            __threadfence();                   // acquire
        }
        __syncthreads();
    };

    // ---- one half Sinkhorn update (bit-identical math to R5) ----
    auto half_phase = [&](const float4* rows, float4* cols,
                          const float* pot_in, float* pot_out, bool read_pot) {
        float w[4]; float lmax = -3.4e38f;
        #pragma unroll
        for (int r = 0; r < 4; ++r) {
            int j = tid + 256 * r;
            w[r] = read_pot ? pot_in[j] * K2 : 0.f;
            lmax = fmaxf(lmax, w[r]);
        }
        lmax = wave_max(lmax);
        if (lane == 0) wred[wave] = lmax;
        __syncthreads();
        const float S = fmaxf(fmaxf(wred[0], wred[1]),
                              fmaxf(wred[2], wred[3])) - 60.0f;
        #pragma unroll
        for (int r = 0; r < 4; ++r) {
            int j = tid + 256 * r;
            reinterpret_cast<float*>(&cols[j])[3] = w[r] - S;
        }
        __syncthreads();

        float tx[RPW], ty[RPW], tz[RPW], s[RPW];
        #pragma unroll
        for (int r = 0; r < RPW; ++r) {
            float4 p = rows[i0 + r];           // broadcast read
            tx[r] = p.x; ty[r] = p.y; tz[r] = p.z; s[r] = 0.f;
        }
        #pragma unroll 4
        for (int k = 0; k < 16; ++k) {
            float4 c = cols[lane + 64 * k];
            #pragma unroll
            for (int r = 0; r < RPW; ++r) {
                float dx = tx[r] - c.x, dy = ty[r] - c.y, dz = tz[r] - c.z;
                float d2 = fmaf(dx, dx, fmaf(dy, dy, fmaf(dz, dz, 1e-12f)));
                float C  = __builtin_amdgcn_sqrtf(d2);
                float arg = fmaf(C, -K2, c.w);
                s[r] += __builtin_amdgcn_exp2f(arg);
            }
        }
        #pragma unroll
        for (int r = 0; r < RPW; ++r) s[r] = wave_sum(s[r]);
        if (lane == 0) {
            #pragma unroll
            for (int r = 0; r < RPW; ++r) {
                float lse = (S + __builtin_amdgcn_logf(s[r])) * LN2;
                pot_out[i0 + r] = EPS * (LOGMARG - lse);
            }
        }
    };

    int phase = 0;
    for (int it = 0; it < ITERS; ++it) {
        half_phase(tp, sp, gb, fb, it > 0);  // f-update (g==0 on iter 0)
        barrier(++phase);
        half_phase(sp, tp, fb, gb, true);    // g-update
        barrier(++phase);
    }

    // ---- fused final: acc += sum_ij C_ij * exp((f_i + g_j - C_ij)/EPS) ----
    {
        float w[4]; float lmax = -3.4e38f;
        #pragma unroll
        for (int r = 0; r < 4; ++r) {
            int j = tid + 256 * r;
            w[r] = gb[j] * K2;
            lmax = fmaxf(lmax, w[r]);
        }
        lmax = wave_max(lmax);
        if (lane == 0) wred[wave] = lmax;
        __syncthreads();
        const float S = fmaxf(fmaxf(wred[0], wred[1]),
                              fmaxf(wred[2], wred[3])) - 60.0f;
        #pragma unroll
        for (int r = 0; r < 4; ++r) {
            int j = tid + 256 * r;
            reinterpret_cast<float*>(&sp[j])[3] = w[r] - S;
        }
        __syncthreads();

        float tx[RPW], ty[RPW], tz[RPW], loc[RPW];
        #pragma unroll
        for (int r = 0; r < RPW; ++r) {
            float4 p = tp[i0 + r];
            tx[r] = p.x; ty[r] = p.y; tz[r] = p.z; loc[r] = 0.f;
        }
        #pragma unroll 4
        for (int k = 0; k < 16; ++k) {
            float4 c = sp[lane + 64 * k];
            #pragma unroll
            for (int r = 0; r < RPW; ++r) {
                float dx = tx[r] - c.x, dy = ty[r] - c.y, dz = tz[r] - c.z;
                float d2 = fmaf(dx, dx, fmaf(dy, dy, fmaf(dz, dz, 1e-12f)));
                float C  = __builtin_amdgcn_sqrtf(d2);
                float p  = __builtin_amdgcn_exp2f(fmaf(C, -K2, c.w));
                loc[r] = fmaf(p, C, loc[r]);
            }
        }
        float wtot = 0.f;
        #pragma unroll
        for (int r = 0; r < RPW; ++r) {
            float sc = __builtin_amdgcn_exp2f(fmaf(fb[i0 + r], K2, S));
            wtot = fmaf(sc, loc[r], wtot);
        }
        wtot = wave_sum(wtot);
        if (lane == 0) wred[wave] = wtot;
        __syncthreads();
        if (tid == 0) {
            float t = wred[0] + wred[1] + wred[2] + wred[3];
            atomicAdd(acc, t);
            __threadfence();
            unsigned o = atomicAdd(done, 1u);
            if (o == NWG - 1) {                    // last WG: all adds done
                __threadfence();
                float a = atomicAdd(acc, 0.0f);    // coherent read
                out[0] = a * (1.0f / ((float)BATCH * (float)NPT));
            }
        }
    }
}

// ======================= fallback multi-launch path (R5) ===================
__global__ __launch_bounds__(256) void sinkhorn_half(
    const float* __restrict__ row_pts, const float* __restrict__ col_pts,
    const float* __restrict__ col_pot, float* __restrict__ out_pot)
{
    constexpr float LOG2E = 1.4426950408889634f;
    constexpr float LN2   = 0.6931471805599453f;
    constexpr float K2    = LOG2E / EPS;
    constexpr float LOGMARG = -6.93147180559945309f;

    __shared__ float4 cols[NPT];
    __shared__ float  wmax[4];

    const int b  = blockIdx.x / WG_PER_BATCH;
    const int wg = blockIdx.x % WG_PER_BATCH;
    const int tid = threadIdx.x;
    const int wave = tid >> 6;
    const int lane = tid & 63;

    const float* cp = col_pts + (size_t)b * NPT * 3;
    const float* pp = col_pot + (size_t)b * NPT;

    float w[4]; float lmax = -3.4e38f;
    #pragma unroll
    for (int r = 0; r < 4; ++r) {
        int j = tid + 256 * r;
        w[r] = pp[j] * K2;
        lmax = fmaxf(lmax, w[r]);
    }
    lmax = wave_max(lmax);
    if (lane == 0) wmax[wave] = lmax;
    __syncthreads();
    const float S = fmaxf(fmaxf(wmax[0], wmax[1]), fmaxf(wmax[2], wmax[3])) - 60.0f;
    #pragma unroll
    for (int r = 0; r < 4; ++r) {
        int j = tid + 256 * r;
        cols[j] = make_float4(cp[3*j], cp[3*j+1], cp[3*j+2], w[r] - S);
    }
    __syncthreads();

    const float* rp = row_pts + (size_t)b * NPT * 3;
    float* op = out_pot + (size_t)b * NPT;

    const int i0 = wg * ROWS_PER_WG + wave * RPW;
    float tx[RPW], ty[RPW], tz[RPW], s[RPW];
    #pragma unroll
    for (int r = 0; r < RPW; ++r) {
        tx[r] = rp[3*(i0+r)]; ty[r] = rp[3*(i0+r)+1]; tz[r] = rp[3*(i0+r)+2];
        s[r] = 0.f;
    }
    #pragma unroll 4
    for (int k = 0; k < 16; ++k) {
        float4 c = cols[lane + 64 * k];
        #pragma unroll
        for (int r = 0; r < RPW; ++r) {
            float dx = tx[r] - c.x, dy = ty[r] - c.y, dz = tz[r] - c.z;
            float d2 = fmaf(dx, dx, fmaf(dy, dy, fmaf(dz, dz, 1e-12f)));
            float C  = __builtin_amdgcn_sqrtf(d2);
            s[r] += __builtin_amdgcn_exp2f(fmaf(C, -K2, c.w));
        }
    }
    #pragma unroll
    for (int r = 0; r < RPW; ++r) s[r] = wave_sum(s[r]);
    if (lane == 0) {
        #pragma unroll
        for (int r = 0; r < RPW; ++r) {
            float lse = (S + __builtin_amdgcn_logf(s[r])) * LN2;
            op[i0 + r] = EPS * (LOGMARG - lse);
        }
    }
}

__global__ __launch_bounds__(256) void emd_final(
    const float* __restrict__ t_pts, const float* __restrict__ s_pts,
    const float* __restrict__ f, const float* __restrict__ g,
    float* __restrict__ acc)
{
    constexpr float LOG2E = 1.4426950408889634f;
    constexpr float K2    = LOG2E / EPS;

    __shared__ float4 cols[NPT];
    __shared__ float  wmax[4];
    __shared__ float  accsm[4];

    const int b  = blockIdx.x / WG_PER_BATCH;
    const int wg = blockIdx.x % WG_PER_BATCH;
    const int tid = threadIdx.x;
    const int wave = tid >> 6;
    const int lane = tid & 63;

    const float* cp = s_pts + (size_t)b * NPT * 3;
    const float* gp = g + (size_t)b * NPT;

    float w[4]; float lmax = -3.4e38f;
    #pragma unroll
    for (int r = 0; r < 4; ++r) {
        int j = tid + 256 * r;
        w[r] = gp[j] * K2;
        lmax = fmaxf(lmax, w[r]);
    }
    lmax = wave_max(lmax);
    if (lane == 0) wmax[wave] = lmax;
    __syncthreads();
    const float S = fmaxf(fmaxf(wmax[0], wmax[1]), fmaxf(wmax[2], wmax[3])) - 60.0f;
    #pragma unroll
    for (int r = 0; r < 4; ++r) {
        int j = tid + 256 * r;
        cols[j] = make_float4(cp[3*j], cp[3*j+1], cp[3*j+2], w[r] - S);
    }
    __syncthreads();

    const float* rp = t_pts + (size_t)b * NPT * 3;
    const float* fp = f + (size_t)b * NPT;

    const int i0 = wg * ROWS_PER_WG + wave * RPW;
    float tx[RPW], ty[RPW], tz[RPW], loc[RPW];
    #pragma unroll
    for (int r = 0; r < RPW; ++r) {
        tx[r] = rp[3*(i0+r)]; ty[r] = rp[3*(i0+r)+1]; tz[r] = rp[3*(i0+r)+2];
        loc[r] = 0.f;
    }
    #pragma unroll 4
    for (int k = 0; k < 16; ++k) {
        float4 c = cols[lane + 64 * k];
        #pragma unroll
        for (int r = 0; r < RPW; ++r) {
            float dx = tx[r] - c.x, dy = ty[r] - c.y, dz = tz[r] - c.z;
            float d2 = fmaf(dx, dx, fmaf(dy, dy, fmaf(dz, dz, 1e-12f)));
            float C  = __builtin_amdgcn_sqrtf(d2);
            float p  = __builtin_amdgcn_exp2f(fmaf(C, -K2, c.w));
            loc[r] = fmaf(p, C, loc[r]);
        }
    }
    float wtot = 0.f;
    #pragma unroll
    for (int r = 0; r < RPW; ++r) {
        float sc = __builtin_amdgcn_exp2f(fmaf(fp[i0 + r], K2, S));
        wtot = fmaf(sc, loc[r], wtot);
    }
    wtot = wave_sum(wtot);
    if (lane == 0) accsm[wave] = wtot;
    __syncthreads();
    if (tid == 0)
        atomicAdd(acc, accsm[0] + accsm[1] + accsm[2] + accsm[3]);
}

__global__ void finalize_kernel(const float* __restrict__ acc,
                                float* __restrict__ out)
{
    out[0] = acc[0] * (1.0f / ((float)BATCH * (float)NPT));
}

extern "C" void kernel_launch(void* const* d_in, const int* in_sizes, int n_in,
                              void* d_out, int out_size, void* d_ws, size_t ws_size,
                              hipStream_t stream) {
    const float* tmpl = (const float*)d_in[0];   // [32,1024,3]
    const float* src  = (const float*)d_in[1];   // [32,1024,3]
    float* out = (float*)d_out;

    // ws layout: [acc f32][done u32][pad to 64B][bar 32*64B][f][g]
    float*    acc  = (float*)d_ws;
    unsigned* done = (unsigned*)d_ws + 1;
    unsigned* bar  = (unsigned*)d_ws + 16;
    float*    f    = (float*)d_ws + 16 + BATCH * BAR_STRIDE;
    float*    g    = f + BATCH * NPT;

    hipMemsetAsync(d_ws, 0, (16 + BATCH * BAR_STRIDE) * sizeof(unsigned), stream);

    void* args[] = {(void*)&tmpl, (void*)&src, (void*)&f, (void*)&g,
                    (void*)&bar, (void*)&acc, (void*)&done, (void*)&out};
    hipError_t err = hipLaunchCooperativeKernel((const void*)sinkhorn_fused,
                                                dim3(NWG), dim3(256), args, 0,
                                                stream);
    if (err != hipSuccess) {
        // Fallback: measured-good R5 multi-launch path (same math).
        (void)hipGetLastError();  // clear error state
        hipMemsetAsync(g, 0, BATCH * NPT * sizeof(float), stream);
        dim3 grid(NWG); dim3 block(256);
        for (int it = 0; it < ITERS; ++it) {
            sinkhorn_half<<<grid, block, 0, stream>>>(tmpl, src, g, f);
            sinkhorn_half<<<grid, block, 0, stream>>>(src, tmpl, f, g);
        }
        emd_final<<<grid, block, 0, stream>>>(tmpl, src, f, g, acc);
        finalize_kernel<<<1, 1, 0, stream>>>(acc, out);
    }
}

// Round 16
// 1342.826 us; speedup vs baseline: 4.2502x; 4.2502x over previous
//
#include <hip/hip_runtime.h>
#include <math.h>

// Sinkhorn EMD loss, B=32, N=1024, 3-D points, EPS=0.02, 50 iters.
// R14: REVERT to multi-launch skeleton (R5, measured 1358 us; R7's persistent
// cooperative kernel measured 5707 us -- spin barrier ~44us/phase >> ~3-5us
// launch overhead. Persistent path deleted.)
// Single change vs R5: occupancy. RPW 8->4, 16 rows/WG, grid 2048 WGs
// = 8 WG/CU (was 4), __launch_bounds__(256,8). Per-element math bit-identical.

#define BATCH 32
#define NPT 1024
#define EPS 0.02f
#define ITERS 50
#define RPW 4                            // rows per wave
#define ROWS_PER_WG 16                   // 4 waves * RPW
#define WG_PER_BATCH (NPT / ROWS_PER_WG) // 64
#define NWG (BATCH * WG_PER_BATCH)       // 2048

static __device__ __forceinline__ float wave_max(float v) {
    #pragma unroll
    for (int off = 32; off > 0; off >>= 1)
        v = fmaxf(v, __shfl_xor(v, off, 64));
    return v;
}
static __device__ __forceinline__ float wave_sum(float v) {
    #pragma unroll
    for (int off = 32; off > 0; off >>= 1)
        v += __shfl_xor(v, off, 64);
    return v;
}

// out_pot[b][i] = EPS*(log_marg - logsumexp_j((col_pot[b][j] - C(b,i,j))/EPS))
// C = sqrt(|row_pts_i - col_pts_j|^2 + 1e-12).
// 4 waves/WG, each wave owns 4 rows processed simultaneously over the k-loop.
__global__ __launch_bounds__(256, 8) void sinkhorn_half(
    const float* __restrict__ row_pts,   // [B][N][3]
    const float* __restrict__ col_pts,   // [B][N][3]
    const float* __restrict__ col_pot,   // [B][N]
    float* __restrict__ out_pot)         // [B][N]
{
    constexpr float LOG2E = 1.4426950408889634f;
    constexpr float LN2   = 0.6931471805599453f;
    constexpr float K2    = LOG2E / EPS;             // exp2-domain scale
    constexpr float LOGMARG = -6.93147180559945309f; // ln(1/1024)

    __shared__ float4 cols[NPT];   // {x, y, z, pot*K2 - S}  16 KB
    __shared__ float  wmax[4];

    const int b  = blockIdx.x / WG_PER_BATCH;
    const int wg = blockIdx.x % WG_PER_BATCH;
    const int tid = threadIdx.x;
    const int wave = tid >> 6;
    const int lane = tid & 63;

    const float* cp = col_pts + (size_t)b * NPT * 3;
    const float* pp = col_pot + (size_t)b * NPT;

    // Stage: pot*K2 to registers, block-max, one LDS write with S folded.
    float w[4];
    float lmax = -3.4e38f;
    #pragma unroll
    for (int r = 0; r < 4; ++r) {
        int j = tid + 256 * r;
        w[r] = pp[j] * K2;
        lmax = fmaxf(lmax, w[r]);
    }
    lmax = wave_max(lmax);
    if (lane == 0) wmax[wave] = lmax;
    __syncthreads();
    // Shift S: terms exp2(pot*K2 - C*K2 - S) <= 2^60 (no overflow) and the
    // argmax-j term >= 2^(60 - sqrt(3)*K2) = 2^-64.9 (no fatal underflow).
    const float S = fmaxf(fmaxf(wmax[0], wmax[1]), fmaxf(wmax[2], wmax[3])) - 60.0f;
    #pragma unroll
    for (int r = 0; r < 4; ++r) {
        int j = tid + 256 * r;
        cols[j] = make_float4(cp[3*j], cp[3*j+1], cp[3*j+2], w[r] - S);
    }
    __syncthreads();

    const float* rp = row_pts + (size_t)b * NPT * 3;
    float* op = out_pot + (size_t)b * NPT;

    const int i0 = wg * ROWS_PER_WG + wave * RPW;
    float tx[RPW], ty[RPW], tz[RPW], s[RPW];
    #pragma unroll
    for (int r = 0; r < RPW; ++r) {
        tx[r] = rp[3*(i0+r)]; ty[r] = rp[3*(i0+r)+1]; tz[r] = rp[3*(i0+r)+2];
        s[r] = 0.f;
    }

    #pragma unroll 4
    for (int k = 0; k < 16; ++k) {
        float4 c = cols[lane + 64 * k];
        #pragma unroll
        for (int r = 0; r < RPW; ++r) {
            float dx = tx[r] - c.x, dy = ty[r] - c.y, dz = tz[r] - c.z;
            float d2 = fmaf(dx, dx, fmaf(dy, dy, fmaf(dz, dz, 1e-12f)));
            float C  = __builtin_amdgcn_sqrtf(d2);
            float arg = fmaf(C, -K2, c.w);
            s[r] += __builtin_amdgcn_exp2f(arg);
        }
    }
    #pragma unroll
    for (int r = 0; r < RPW; ++r) s[r] = wave_sum(s[r]);
    if (lane == 0) {
        #pragma unroll
        for (int r = 0; r < RPW; ++r) {
            float lse = (S + __builtin_amdgcn_logf(s[r])) * LN2;  // natural-log LSE
            op[i0 + r] = EPS * (LOGMARG - lse);
        }
    }
}

// acc += sum_ij C_ij * exp((f_i + g_j - C_ij)/EPS)
__global__ __launch_bounds__(256, 8) void emd_final(
    const float* __restrict__ t_pts,   // [B][N][3]
    const float* __restrict__ s_pts,   // [B][N][3]
    const float* __restrict__ f,       // [B][N]
    const float* __restrict__ g,       // [B][N]
    float* __restrict__ acc)
{
    constexpr float LOG2E = 1.4426950408889634f;
    constexpr float K2    = LOG2E / EPS;

    __shared__ float4 cols[NPT];   // {x, y, z, g*K2 - S}
    __shared__ float  wmax[4];
    __shared__ float  accsm[4];

    const int b  = blockIdx.x / WG_PER_BATCH;
    const int wg = blockIdx.x % WG_PER_BATCH;
    const int tid = threadIdx.x;
    const int wave = tid >> 6;
    const int lane = tid & 63;

    const float* cp = s_pts + (size_t)b * NPT * 3;
    const float* gp = g + (size_t)b * NPT;

    float w[4];
    float lmax = -3.4e38f;
    #pragma unroll
    for (int r = 0; r < 4; ++r) {
        int j = tid + 256 * r;
        w[r] = gp[j] * K2;
        lmax = fmaxf(lmax, w[r]);
    }
    lmax = wave_max(lmax);
    if (lane == 0) wmax[wave] = lmax;
    __syncthreads();
    const float S = fmaxf(fmaxf(wmax[0], wmax[1]), fmaxf(wmax[2], wmax[3])) - 60.0f;
    #pragma unroll
    for (int r = 0; r < 4; ++r) {
        int j = tid + 256 * r;
        cols[j] = make_float4(cp[3*j], cp[3*j+1], cp[3*j+2], w[r] - S);
    }
    __syncthreads();

    const float* rp = t_pts + (size_t)b * NPT * 3;
    const float* fp = f + (size_t)b * NPT;

    const int i0 = wg * ROWS_PER_WG + wave * RPW;
    float tx[RPW], ty[RPW], tz[RPW], loc[RPW];
    #pragma unroll
    for (int r = 0; r < RPW; ++r) {
        tx[r] = rp[3*(i0+r)]; ty[r] = rp[3*(i0+r)+1]; tz[r] = rp[3*(i0+r)+2];
        loc[r] = 0.f;
    }

    #pragma unroll 4
    for (int k = 0; k < 16; ++k) {
        float4 c = cols[lane + 64 * k];
        #pragma unroll
        for (int r = 0; r < RPW; ++r) {
            float dx = tx[r] - c.x, dy = ty[r] - c.y, dz = tz[r] - c.z;
            float d2 = fmaf(dx, dx, fmaf(dy, dy, fmaf(dz, dz, 1e-12f)));
            float C  = __builtin_amdgcn_sqrtf(d2);
            float p  = __builtin_amdgcn_exp2f(fmaf(C, -K2, c.w));
            loc[r] = fmaf(p, C, loc[r]);   // sum_j C * 2^(g K2 - S - C K2)
        }
    }
    // per-row scale 2^(f_i K2 + S), summed within the wave
    float wtot = 0.f;
    #pragma unroll
    for (int r = 0; r < RPW; ++r) {
        float sc = __builtin_amdgcn_exp2f(fmaf(fp[i0 + r], K2, S));
        wtot = fmaf(sc, loc[r], wtot);
    }
    wtot = wave_sum(wtot);
    if (lane == 0) accsm[wave] = wtot;
    __syncthreads();
    if (tid == 0) {
        float t = accsm[0] + accsm[1] + accsm[2] + accsm[3];
        atomicAdd(acc, t);
    }
}

__global__ void finalize_kernel(const float* __restrict__ acc,
                                float* __restrict__ out)
{
    out[0] = acc[0] * (1.0f / ((float)BATCH * (float)NPT));
}

extern "C" void kernel_launch(void* const* d_in, const int* in_sizes, int n_in,
                              void* d_out, int out_size, void* d_ws, size_t ws_size,
                              hipStream_t stream) {
    const float* tmpl = (const float*)d_in[0];   // [32,1024,3]
    const float* src  = (const float*)d_in[1];   // [32,1024,3]
    float* out = (float*)d_out;

    float* f   = (float*)d_ws;               // [B*N]
    float* g   = f + BATCH * NPT;            // [B*N]
    float* acc = g + BATCH * NPT;            // [1]

    hipMemsetAsync(g, 0, BATCH * NPT * sizeof(float), stream);
    hipMemsetAsync(acc, 0, sizeof(float), stream);

    dim3 grid(NWG);   // 2048 WGs = 8 per CU
    dim3 block(256);

    for (int it = 0; it < ITERS; ++it) {
        sinkhorn_half<<<grid, block, 0, stream>>>(tmpl, src, g, f);
        sinkhorn_half<<<grid, block, 0, stream>>>(src, tmpl, f, g);
    }
    emd_final<<<grid, block, 0, stream>>>(tmpl, src, f, g, acc);
    finalize_kernel<<<1, 1, 0, stream>>>(acc, out);
}